// Round 6
// baseline (589.600 us; speedup 1.0000x reference)
//
#include <hip/hip_runtime.h>
#include <stdint.h>

#define DIM 512
#define ROWS_PER_BLOCK 64                // 4 waves x 16 rows
#define N_CHUNKS 32                      // 32 chunks of 16 e-columns
#define CHUNK_BYTES 8192                 // 16 rows x 512 fp8 (atom-rotated, no pad)
#define WS_BYTES (N_CHUNKS * CHUNK_BYTES)   // 262144 (R image)
#define N_BUF 4                          // LDS ring buffers (32 KB total)
#define PREFETCH 3                       // stage depth: chunk EB+3 in flight

typedef __attribute__((ext_vector_type(4))) float f32x4;
typedef __attribute__((ext_vector_type(2))) float f32x2;
typedef __attribute__((ext_vector_type(4))) int   i32x4;

// k-permutation (validated): position q = g*8+j within 32-k block kk holds
// k = 32*kk + (j<4 ? 4g+j : 16+4g+(j-4)). Puts epilogue value delta[r][e]
// in-lane: e = 16*eb + 4g + i  <->  frag[eb>>1], byte (eb&1)*4 + i.
static __device__ __forceinline__ int kperm(int kk, int q) {
  int g = q >> 3, j = q & 7;
  int r = (j < 4) ? (g * 4 + j) : (16 + g * 4 + (j - 4));
  return kk * 32 + r;
}

// Build fp8 image of 64*(S - I), pre-swizzled: chunk -> 16 rows (e_l) x 512 B.
// Within a row, 16B atom (P,g) [atom index 4P+g] is stored at physical slot
// ((4P+g)+e_l)&31 — per-row rotation spreads the K-loop's b128 reads over banks.
__global__ void prep_R(const float* __restrict__ S, uint32_t* __restrict__ ws) {
  int idx = blockIdx.x * blockDim.x + threadIdx.x;   // word index
  if (idx >= WS_BYTES / 4) return;
  int b     = idx * 4;
  int chunk = b >> 13;
  int e_l   = (b >> 9) & 15;
  int inrow = b & 511;
  int slot  = inrow >> 4;
  int bia   = inrow & 15;                // byte-in-atom base (0,4,8,12)
  int la    = (slot - e_l) & 31;         // logical atom = 4P+g
  int P = la >> 2, g = la & 3;
  int e = chunk * 16 + e_l;
  float v[4];
#pragma unroll
  for (int t = 0; t < 4; ++t) {
    int bb = bia + t;                    // byte in atom 0..15
    int j  = bb & 7;
    int kk = 2 * P + (bb >> 3);
    int k  = kperm(kk, g * 8 + j);
    v[t] = 64.0f * (S[k * DIM + e] - (k == e ? 1.0f : 0.0f));   // x64: e4m3 range
  }
  int w = __builtin_amdgcn_cvt_pk_fp8_f32(v[0], v[1], 0, false);
  w     = __builtin_amdgcn_cvt_pk_fp8_f32(v[2], v[3], w, true);
  ws[idx] = (uint32_t)w;
}

// Nontemporal load: X/XF have zero reuse and sit at the L3 capacity cliff
// (268 MB vs 256 MB L3). Cached streaming ran at 1.1-1.65 TB/s HBM with 50%
// L3 hit (rounds 3-4, FETCH = half of input); nt gives a clean all-HBM stream
// (round 5: delta_pack 102 -> <78 us with this one change).
static __device__ __forceinline__ f32x4 ntload(const f32x4* p) {
  return __builtin_nontemporal_load(p);
}

// Stage one 8 KB R-chunk into LDS (async direct-to-LDS, width 16, linear).
static __device__ __forceinline__ void stage_chunk(const uint32_t* __restrict__ ws,
                                                   int eb, char* dst, int tid) {
  const uint32_t* src = ws + (size_t)eb * (CHUNK_BYTES / 4);
#pragma unroll
  for (int r = 0; r < 2; ++r) {                      // 512 x 16B slots
    int idx = r * 256 + tid;
    __builtin_amdgcn_global_load_lds(
        (const __attribute__((address_space(1))) void*)(src + idx * 4),
        (__attribute__((address_space(3))) void*)(dst + idx * 16),
        16, 0, 0);
  }
}

// ---- Phase 0 (template-unrolled, constant frag indices). Identical
// arithmetic/order to the validated round-3 version; only the loads carry nt. ----
template <int KK>
struct P0 {
  static __device__ __forceinline__ void run(const float* __restrict__ xr,
                                             const float* __restrict__ fr,
                                             int g, long long (&fragL)[16], float& sumsq) {
    const f32x4 a0 = ntload((const f32x4*)(xr + KK * 32 + 4 * g));
    const f32x4 b0 = ntload((const f32x4*)(fr + KK * 32 + 4 * g));
    const f32x4 a1 = ntload((const f32x4*)(xr + KK * 32 + 16 + 4 * g));
    const f32x4 b1 = ntload((const f32x4*)(fr + KK * 32 + 16 + 4 * g));
    float d0 = a0[0] - b0[0], d1 = a0[1] - b0[1], d2 = a0[2] - b0[2], d3 = a0[3] - b0[3];
    float d4 = a1[0] - b1[0], d5 = a1[1] - b1[1], d6 = a1[2] - b1[2], d7 = a1[3] - b1[3];
    sumsq += d0*d0 + d1*d1 + d2*d2 + d3*d3 + d4*d4 + d5*d5 + d6*d6 + d7*d7;
    int lo = __builtin_amdgcn_cvt_pk_fp8_f32(d0, d1, 0, false);
    lo     = __builtin_amdgcn_cvt_pk_fp8_f32(d2, d3, lo, true);
    int hi = __builtin_amdgcn_cvt_pk_fp8_f32(d4, d5, 0, false);
    hi     = __builtin_amdgcn_cvt_pk_fp8_f32(d6, d7, hi, true);
    fragL[KK] = (long long)(((unsigned long long)(unsigned)hi << 32) | (unsigned)lo);
    P0<KK + 1>::run(xr, fr, g, fragL, sumsq);
  }
};
template <>
struct P0<16> {
  static __device__ __forceinline__ void run(const float*, const float*, int,
                                             long long (&)[16], float&) {}
};

// ---- K-loop over 8 atom-steps; each b128 feeds two fp8 MFMAs ----
template <int P>
struct KLoop {
  static __device__ __forceinline__ void run(const char* __restrict__ rowbase,
                                             int g, int m,
                                             const long long (&fragL)[16],
                                             f32x4& c0, f32x4& c1) {
    int off = ((4 * P + g + m) & 31) * 16;           // rotated atom slot
    i32x4 a = *(const i32x4*)(rowbase + off);
    long long A0 = (long long)(((unsigned long long)(unsigned)a[1] << 32) | (unsigned)a[0]);
    long long A1 = (long long)(((unsigned long long)(unsigned)a[3] << 32) | (unsigned)a[2]);
    c0 = __builtin_amdgcn_mfma_f32_16x16x32_fp8_fp8(A0, fragL[2 * P],     c0, 0, 0, 0);
    c1 = __builtin_amdgcn_mfma_f32_16x16x32_fp8_fp8(A1, fragL[2 * P + 1], c1, 0, 0, 0);
    KLoop<P + 1>::run(rowbase, g, m, fragL, c0, c1);
  }
};
template <>
struct KLoop<8> {
  static __device__ __forceinline__ void run(const char*, int, int,
                                             const long long (&)[16], f32x4&, f32x4&) {}
};

// ---- Chunk loop: 4-buffer LDS ring, depth-3 prefetch, ONE raw s_barrier per
// chunk with counted vmcnt (round-3 validated). Prologue stage loads are OLDER
// in the vmcnt FIFO than P0's nt loads, so P0's own consumption waits drain
// them — the counted waits below remain conservative-safe. ----
template <int EB>
struct ChunkLoop {
  static __device__ __forceinline__ void run(const uint32_t* __restrict__ ws,
                                             char* __restrict__ sbase,
                                             int tid, int m, int g,
                                             const long long (&fragL)[16], float& part) {
    if constexpr (EB <= N_CHUNKS - 3)
      asm volatile("s_waitcnt vmcnt(4) lgkmcnt(0)" ::: "memory");
    else if constexpr (EB == N_CHUNKS - 2)
      asm volatile("s_waitcnt vmcnt(2) lgkmcnt(0)" ::: "memory");
    else
      asm volatile("s_waitcnt vmcnt(0) lgkmcnt(0)" ::: "memory");
    __builtin_amdgcn_s_barrier();

    if constexpr (EB + PREFETCH < N_CHUNKS)
      stage_chunk(ws, EB + PREFETCH,
                  sbase + ((EB + PREFETCH) & (N_BUF - 1)) * CHUNK_BYTES, tid);

    const char* rowbase = sbase + (EB & (N_BUF - 1)) * CHUNK_BYTES + m * 512;
    f32x4 c0 = {0.f, 0.f, 0.f, 0.f}, c1 = {0.f, 0.f, 0.f, 0.f};
    KLoop<0>::run(rowbase, g, m, fragL, c0, c1);

    // Epilogue: C row (g*4+i)=e_local; delta[r][e] is byte (EB&1)*4+i of fragL[EB>>1].
    constexpr int kk = EB >> 1;
    int src = (int)(fragL[kk] >> ((EB & 1) * 32));
    f32x2 f01 = __builtin_amdgcn_cvt_pk_f32_fp8(src, false);
    f32x2 f23 = __builtin_amdgcn_cvt_pk_f32_fp8(src, true);
    part += (c0[0] + c1[0]) * f01[0] + (c0[1] + c1[1]) * f01[1]
          + (c0[2] + c1[2]) * f23[0] + (c0[3] + c1[3]) * f23[1];

    ChunkLoop<EB + 1>::run(ws, sbase, tid, m, g, fragL, part);
  }
};
template <>
struct ChunkLoop<N_CHUNKS> {
  static __device__ __forceinline__ void run(const uint32_t*, char*, int, int, int,
                                             const long long (&)[16], float&) {}
};

// out[row] = fp32 sumsq(delta) + (1/64) * delta^T (64R) delta  via fp8 MFMA.
// Fused again (round-3 structure, 123 us) + nt streaming (round-5 fix): the
// split's 34 MB image write + 34 MB read + extra launch are pure overhead once
// the stream runs at nt rate. Rounds 3 vs 4 showed streaming rate is
// L3-mix-limited, not occupancy-limited, so (256,2) is fine here.
__global__ __launch_bounds__(256, 2)
void mahal_main(const float* __restrict__ X, const float* __restrict__ XF,
                const uint32_t* __restrict__ ws, float* __restrict__ out) {
  __shared__ __align__(16) char sA[N_BUF][CHUNK_BYTES];   // 32 KB

  const int tid  = threadIdx.x;
  const int lane = tid & 63;
  const int wv   = tid >> 6;
  const int m    = lane & 15;          // delta row within wave
  const int g    = lane >> 4;          // lane group
  const int row  = blockIdx.x * ROWS_PER_BLOCK + wv * 16 + m;

  const float* xr = X  + (size_t)row * DIM;
  const float* fr = XF + (size_t)row * DIM;

  // Prologue: 3 chunks in flight; their L2 latency hides under P0's stream.
  stage_chunk(ws, 0, sA[0], tid);
  stage_chunk(ws, 1, sA[1], tid);
  stage_chunk(ws, 2, sA[2], tid);

  long long fragL[16];
  float sumsq = 0.f;
  P0<0>::run(xr, fr, g, fragL, sumsq);
  sumsq += __shfl_xor(sumsq, 16);
  sumsq += __shfl_xor(sumsq, 32);

  float part = 0.f;
  ChunkLoop<0>::run(ws, &sA[0][0], tid, m, g, fragL, part);

  part += __shfl_xor(part, 16);
  part += __shfl_xor(part, 32);
  if (g == 0) out[row] = sumsq + part * 0.015625f;   // 1/64 undoes R scaling
}

// Safety-net (only if ws_size is unexpectedly small): naive fp32, correct.
__global__ void mahal_naive(const float* __restrict__ X, const float* __restrict__ XF,
                            const float* __restrict__ S, float* __restrict__ out, int n) {
  int row = blockIdx.x * blockDim.x + threadIdx.x;
  if (row >= n) return;
  const float* xr = X + (size_t)row * DIM;
  const float* fr = XF + (size_t)row * DIM;
  float acc = 0.f;
  for (int d = 0; d < DIM; ++d) {
    float dd = xr[d] - fr[d];
    float inner = 0.f;
    for (int e = 0; e < DIM; ++e) inner += S[d * DIM + e] * (xr[e] - fr[e]);
    acc += dd * inner;
  }
  out[row] = acc;
}

extern "C" void kernel_launch(void* const* d_in, const int* in_sizes, int n_in,
                              void* d_out, int out_size, void* d_ws, size_t ws_size,
                              hipStream_t stream) {
  const float* X  = (const float*)d_in[0];
  const float* XF = (const float*)d_in[1];
  const float* S  = (const float*)d_in[2];
  float* out = (float*)d_out;
  const int N = in_sizes[0] / DIM;

  if (ws_size < (size_t)WS_BYTES || (N % ROWS_PER_BLOCK) != 0) {
    mahal_naive<<<(N + 63) / 64, 64, 0, stream>>>(X, XF, S, out, N);
    return;
  }

  uint32_t* ws = (uint32_t*)d_ws;
  prep_R<<<(WS_BYTES / 4 + 255) / 256, 256, 0, stream>>>(S, ws);
  mahal_main<<<N / ROWS_PER_BLOCK, 256, 0, stream>>>(X, XF, ws, out);
}

// Round 8
// 588.270 us; speedup vs baseline: 1.0023x; 1.0023x over previous
//
#include <hip/hip_runtime.h>
#include <stdint.h>

#define DIM 512
#define ROWS_PER_BLOCK 64                // 4 waves x 16 rows
#define N_CHUNKS 32                      // 32 chunks of 16 e-columns
#define CHUNK_BYTES 8192                 // 16 rows x 512 fp8 (atom-rotated, no pad)
#define WS_BYTES (N_CHUNKS * CHUNK_BYTES)   // 262144 (R image)
#define N_BUF 4                          // LDS ring buffers (32 KB total)
#define PREFETCH 3                       // stage depth: chunk EB+3 in flight

typedef __attribute__((ext_vector_type(4))) float f32x4;
typedef __attribute__((ext_vector_type(2))) float f32x2;
typedef __attribute__((ext_vector_type(4))) int   i32x4;

// k-permutation (validated): position q = g*8+j within 32-k block kk holds
// k = 32*kk + (j<4 ? 4g+j : 16+4g+(j-4)). Puts epilogue value delta[r][e]
// in-lane: e = 16*eb + 4g + i  <->  frag[eb>>1], byte (eb&1)*4 + i.
static __device__ __forceinline__ int kperm(int kk, int q) {
  int g = q >> 3, j = q & 7;
  int r = (j < 4) ? (g * 4 + j) : (16 + g * 4 + (j - 4));
  return kk * 32 + r;
}

// Build fp8 image of 64*(S - I), pre-swizzled: chunk -> 16 rows (e_l) x 512 B.
// Within a row, 16B atom (P,g) [atom index 4P+g] is stored at physical slot
// ((4P+g)+e_l)&31 — per-row rotation spreads the K-loop's b128 reads over banks.
__global__ void prep_R(const float* __restrict__ S, uint32_t* __restrict__ ws) {
  int idx = blockIdx.x * blockDim.x + threadIdx.x;   // word index
  if (idx >= WS_BYTES / 4) return;
  int b     = idx * 4;
  int chunk = b >> 13;
  int e_l   = (b >> 9) & 15;
  int inrow = b & 511;
  int slot  = inrow >> 4;
  int bia   = inrow & 15;                // byte-in-atom base (0,4,8,12)
  int la    = (slot - e_l) & 31;         // logical atom = 4P+g
  int P = la >> 2, g = la & 3;
  int e = chunk * 16 + e_l;
  float v[4];
#pragma unroll
  for (int t = 0; t < 4; ++t) {
    int bb = bia + t;                    // byte in atom 0..15
    int j  = bb & 7;
    int kk = 2 * P + (bb >> 3);
    int k  = kperm(kk, g * 8 + j);
    v[t] = 64.0f * (S[k * DIM + e] - (k == e ? 1.0f : 0.0f));   // x64: e4m3 range
  }
  int w = __builtin_amdgcn_cvt_pk_fp8_f32(v[0], v[1], 0, false);
  w     = __builtin_amdgcn_cvt_pk_fp8_f32(v[2], v[3], w, true);
  ws[idx] = (uint32_t)w;
}

// Nontemporal load: X/XF have zero reuse and sit at the L3 capacity cliff
// (268 MB vs 256 MB L3). Cached streaming ran at 1.1-1.65 TB/s HBM with 50%
// L3 hit (rounds 3-4); nt gives a clean all-HBM stream (round-5 delta_pack:
// 102 -> <78 us from this one change; round-6 FETCH confirms the bypass).
// NOTE: must use ext_vector f32x4 — __builtin_nontemporal_load rejects HIP's
// float4 struct (round-7 compile error).
static __device__ __forceinline__ f32x4 ntload4(const float* p) {
  return __builtin_nontemporal_load((const f32x4*)p);
}

// Stage one 8 KB R-chunk into LDS (async direct-to-LDS, width 16, linear).
static __device__ __forceinline__ void stage_chunk(const uint32_t* __restrict__ ws,
                                                   int eb, char* dst, int tid) {
  const uint32_t* src = ws + (size_t)eb * (CHUNK_BYTES / 4);
#pragma unroll
  for (int r = 0; r < 2; ++r) {                      // 512 x 16B slots
    int idx = r * 256 + tid;
    __builtin_amdgcn_global_load_lds(
        (const __attribute__((address_space(1))) void*)(src + idx * 4),
        (__attribute__((address_space(3))) void*)(dst + idx * 16),
        16, 0, 0);
  }
}

// ---- Phase 0 (template-unrolled). Round-6 lesson: nt loads WITHOUT schedule
// pinning let the scheduler hoist/cluster all 64 loads -> VGPR 128 cap hit ->
// 648 MB scratch spill (2.4 KB/thread), 419 us. Fix: sched_barrier(0) after
// each iteration's consume caps in-flight loads at 4/wave (live ~16 regs +
// fragL). Latency check: 8 waves/CU x 4 loads x 1KB = 32 KB/CU in flight >>
// ~9 KB needed for 6.3 TB/s — TLP hides the per-iter wait; HBM still gates. ----
template <int KK>
struct P0 {
  static __device__ __forceinline__ void run(const float* __restrict__ xr,
                                             const float* __restrict__ fr,
                                             int g, long long (&fragL)[16], float& sumsq) {
    const f32x4 a0 = ntload4(xr + KK * 32 + 4 * g);
    const f32x4 b0 = ntload4(fr + KK * 32 + 4 * g);
    const f32x4 a1 = ntload4(xr + KK * 32 + 16 + 4 * g);
    const f32x4 b1 = ntload4(fr + KK * 32 + 16 + 4 * g);
    float d0 = a0[0] - b0[0], d1 = a0[1] - b0[1], d2 = a0[2] - b0[2], d3 = a0[3] - b0[3];
    float d4 = a1[0] - b1[0], d5 = a1[1] - b1[1], d6 = a1[2] - b1[2], d7 = a1[3] - b1[3];
    sumsq += d0*d0 + d1*d1 + d2*d2 + d3*d3 + d4*d4 + d5*d5 + d6*d6 + d7*d7;
    int lo = __builtin_amdgcn_cvt_pk_fp8_f32(d0, d1, 0, false);
    lo     = __builtin_amdgcn_cvt_pk_fp8_f32(d2, d3, lo, true);
    int hi = __builtin_amdgcn_cvt_pk_fp8_f32(d4, d5, 0, false);
    hi     = __builtin_amdgcn_cvt_pk_fp8_f32(d6, d7, hi, true);
    fragL[KK] = (long long)(((unsigned long long)(unsigned)hi << 32) | (unsigned)lo);
    __builtin_amdgcn_sched_barrier(0);   // anti-hoist fence: cap live loads
    P0<KK + 1>::run(xr, fr, g, fragL, sumsq);
  }
};
template <>
struct P0<16> {
  static __device__ __forceinline__ void run(const float*, const float*, int,
                                             long long (&)[16], float&) {}
};

// ---- K-loop over 8 atom-steps; each b128 feeds two fp8 MFMAs ----
template <int P>
struct KLoop {
  static __device__ __forceinline__ void run(const char* __restrict__ rowbase,
                                             int g, int m,
                                             const long long (&fragL)[16],
                                             f32x4& c0, f32x4& c1) {
    int off = ((4 * P + g + m) & 31) * 16;           // rotated atom slot
    i32x4 a = *(const i32x4*)(rowbase + off);
    long long A0 = (long long)(((unsigned long long)(unsigned)a[1] << 32) | (unsigned)a[0]);
    long long A1 = (long long)(((unsigned long long)(unsigned)a[3] << 32) | (unsigned)a[2]);
    c0 = __builtin_amdgcn_mfma_f32_16x16x32_fp8_fp8(A0, fragL[2 * P],     c0, 0, 0, 0);
    c1 = __builtin_amdgcn_mfma_f32_16x16x32_fp8_fp8(A1, fragL[2 * P + 1], c1, 0, 0, 0);
    KLoop<P + 1>::run(rowbase, g, m, fragL, c0, c1);
  }
};
template <>
struct KLoop<8> {
  static __device__ __forceinline__ void run(const char*, int, int,
                                             const long long (&)[16], f32x4&, f32x4&) {}
};

// ---- Chunk loop: 4-buffer LDS ring, depth-3 prefetch, ONE raw s_barrier per
// chunk with counted vmcnt (round-3 validated). P0's loads are fully drained
// by its own data deps before ChunkLoop<0>, so the counted waits are safe. ----
template <int EB>
struct ChunkLoop {
  static __device__ __forceinline__ void run(const uint32_t* __restrict__ ws,
                                             char* __restrict__ sbase,
                                             int tid, int m, int g,
                                             const long long (&fragL)[16], float& part) {
    if constexpr (EB <= N_CHUNKS - 3)
      asm volatile("s_waitcnt vmcnt(4) lgkmcnt(0)" ::: "memory");
    else if constexpr (EB == N_CHUNKS - 2)
      asm volatile("s_waitcnt vmcnt(2) lgkmcnt(0)" ::: "memory");
    else
      asm volatile("s_waitcnt vmcnt(0) lgkmcnt(0)" ::: "memory");
    __builtin_amdgcn_s_barrier();

    if constexpr (EB + PREFETCH < N_CHUNKS)
      stage_chunk(ws, EB + PREFETCH,
                  sbase + ((EB + PREFETCH) & (N_BUF - 1)) * CHUNK_BYTES, tid);

    const char* rowbase = sbase + (EB & (N_BUF - 1)) * CHUNK_BYTES + m * 512;
    f32x4 c0 = {0.f, 0.f, 0.f, 0.f}, c1 = {0.f, 0.f, 0.f, 0.f};
    KLoop<0>::run(rowbase, g, m, fragL, c0, c1);

    // Epilogue: C row (g*4+i)=e_local; delta[r][e] is byte (EB&1)*4+i of fragL[EB>>1].
    constexpr int kk = EB >> 1;
    int src = (int)(fragL[kk] >> ((EB & 1) * 32));
    f32x2 f01 = __builtin_amdgcn_cvt_pk_f32_fp8(src, false);
    f32x2 f23 = __builtin_amdgcn_cvt_pk_f32_fp8(src, true);
    part += (c0[0] + c1[0]) * f01[0] + (c0[1] + c1[1]) * f01[1]
          + (c0[2] + c1[2]) * f23[0] + (c0[3] + c1[3]) * f23[1];

    ChunkLoop<EB + 1>::run(ws, sbase, tid, m, g, fragL, part);
  }
};
template <>
struct ChunkLoop<N_CHUNKS> {
  static __device__ __forceinline__ void run(const uint32_t*, char*, int, int, int,
                                             const long long (&)[16], float&) {}
};

// out[row] = fp32 sumsq(delta) + (1/64) * delta^T (64R) delta  via fp8 MFMA.
// Fused (round-3 structure, VGPR 100 validated) + nt streaming (round-5 fix)
// + P0 schedule pinning (round-6 spill fix).
__global__ __launch_bounds__(256, 2)
void mahal_main(const float* __restrict__ X, const float* __restrict__ XF,
                const uint32_t* __restrict__ ws, float* __restrict__ out) {
  __shared__ __align__(16) char sA[N_BUF][CHUNK_BYTES];   // 32 KB

  const int tid  = threadIdx.x;
  const int lane = tid & 63;
  const int wv   = tid >> 6;
  const int m    = lane & 15;          // delta row within wave
  const int g    = lane >> 4;          // lane group
  const int row  = blockIdx.x * ROWS_PER_BLOCK + wv * 16 + m;

  const float* xr = X  + (size_t)row * DIM;
  const float* fr = XF + (size_t)row * DIM;

  // Prologue: 3 chunks in flight; they complete under P0's stream.
  stage_chunk(ws, 0, sA[0], tid);
  stage_chunk(ws, 1, sA[1], tid);
  stage_chunk(ws, 2, sA[2], tid);

  long long fragL[16];
  float sumsq = 0.f;
  P0<0>::run(xr, fr, g, fragL, sumsq);
  sumsq += __shfl_xor(sumsq, 16);
  sumsq += __shfl_xor(sumsq, 32);

  float part = 0.f;
  ChunkLoop<0>::run(ws, &sA[0][0], tid, m, g, fragL, part);

  part += __shfl_xor(part, 16);
  part += __shfl_xor(part, 32);
  if (g == 0) out[row] = sumsq + part * 0.015625f;   // 1/64 undoes R scaling
}

// Safety-net (only if ws_size is unexpectedly small): naive fp32, correct.
__global__ void mahal_naive(const float* __restrict__ X, const float* __restrict__ XF,
                            const float* __restrict__ S, float* __restrict__ out, int n) {
  int row = blockIdx.x * blockDim.x + threadIdx.x;
  if (row >= n) return;
  const float* xr = X + (size_t)row * DIM;
  const float* fr = XF + (size_t)row * DIM;
  float acc = 0.f;
  for (int d = 0; d < DIM; ++d) {
    float dd = xr[d] - fr[d];
    float inner = 0.f;
    for (int e = 0; e < DIM; ++e) inner += S[d * DIM + e] * (xr[e] - fr[e]);
    acc += dd * inner;
  }
  out[row] = acc;
}

extern "C" void kernel_launch(void* const* d_in, const int* in_sizes, int n_in,
                              void* d_out, int out_size, void* d_ws, size_t ws_size,
                              hipStream_t stream) {
  const float* X  = (const float*)d_in[0];
  const float* XF = (const float*)d_in[1];
  const float* S  = (const float*)d_in[2];
  float* out = (float*)d_out;
  const int N = in_sizes[0] / DIM;

  if (ws_size < (size_t)WS_BYTES || (N % ROWS_PER_BLOCK) != 0) {
    mahal_naive<<<(N + 63) / 64, 64, 0, stream>>>(X, XF, S, out, N);
    return;
  }

  uint32_t* ws = (uint32_t*)d_ws;
  prep_R<<<(WS_BYTES / 4 + 255) / 256, 256, 0, stream>>>(S, ws);
  mahal_main<<<N / ROWS_PER_BLOCK, 256, 0, stream>>>(X, XF, ws, out);
}

// Round 10
// 288.844 us; speedup vs baseline: 2.0412x; 2.0366x over previous
//
#include <hip/hip_runtime.h>
#include <stdint.h>

#define DIM 512
#define ROWS_PER_BLOCK 64                // 4 waves x 16 rows
#define N_CHUNKS 32                      // 32 chunks of 16 e-columns
#define CHUNK_BYTES 8192                 // 16 rows x 512 fp8 (atom-rotated, no pad)
#define WS_BYTES (N_CHUNKS * CHUNK_BYTES)   // 262144 (R image)
#define N_BUF 3                          // LDS ring buffers (24 KB)
#define PREFETCH 2                       // stage depth: chunk EB+2 in flight
#define FRAG_STRIDE 136                  // B/thread frag spill slot (8-aligned)

typedef __attribute__((ext_vector_type(4))) float f32x4;
typedef __attribute__((ext_vector_type(2))) float f32x2;
typedef __attribute__((ext_vector_type(4))) int   i32x4;

// k-permutation (validated): position q = g*8+j within 32-k block kk holds
// k = 32*kk + (j<4 ? 4g+j : 16+4g+(j-4)). Puts epilogue value delta[r][e]
// in-lane: e = 16*eb + 4g + i  <->  frag[eb>>1], byte (eb&1)*4 + i.
static __device__ __forceinline__ int kperm(int kk, int q) {
  int g = q >> 3, j = q & 7;
  int r = (j < 4) ? (g * 4 + j) : (16 + g * 4 + (j - 4));
  return kk * 32 + r;
}

// Build fp8 image of 64*(S - I), pre-swizzled: chunk -> 16 rows (e_l) x 512 B.
// Atom (P,g) of row e_l stored at physical slot ((4P+g)+e_l)&31 (bank spread).
__global__ void prep_R(const float* __restrict__ S, uint32_t* __restrict__ ws) {
  int idx = blockIdx.x * blockDim.x + threadIdx.x;   // word index
  if (idx >= WS_BYTES / 4) return;
  int b     = idx * 4;
  int chunk = b >> 13;
  int e_l   = (b >> 9) & 15;
  int inrow = b & 511;
  int slot  = inrow >> 4;
  int bia   = inrow & 15;                // byte-in-atom base (0,4,8,12)
  int la    = (slot - e_l) & 31;         // logical atom = 4P+g
  int P = la >> 2, g = la & 3;
  int e = chunk * 16 + e_l;
  float v[4];
#pragma unroll
  for (int t = 0; t < 4; ++t) {
    int bb = bia + t;                    // byte in atom 0..15
    int j  = bb & 7;
    int kk = 2 * P + (bb >> 3);
    int k  = kperm(kk, g * 8 + j);
    v[t] = 64.0f * (S[k * DIM + e] - (k == e ? 1.0f : 0.0f));   // x64: e4m3 range
  }
  int w = __builtin_amdgcn_cvt_pk_fp8_f32(v[0], v[1], 0, false);
  w     = __builtin_amdgcn_cvt_pk_fp8_f32(v[2], v[3], w, true);
  ws[idx] = (uint32_t)w;
}

// Nontemporal load: X/XF have zero reuse and sit at the L3 capacity cliff
// (268 MB vs 256 MB L3). Cached streaming: 1.1-1.65 TB/s (rounds 3-4); nt:
// clean all-HBM stream (round-5 delta_pack 102 -> <78 us). ext_vector f32x4
// required — builtin rejects HIP float4 struct (round-7).
static __device__ __forceinline__ f32x4 ntload4(const float* p) {
  return __builtin_nontemporal_load((const f32x4*)p);
}

// Stage one 8 KB R-chunk into LDS (async direct-to-LDS, width 16, linear).
static __device__ __forceinline__ void stage_chunk(const uint32_t* __restrict__ ws,
                                                   int eb, char* dst, int tid) {
  const uint32_t* src = ws + (size_t)eb * (CHUNK_BYTES / 4);
#pragma unroll
  for (int r = 0; r < 2; ++r) {                      // 512 x 16B slots
    int idx = r * 256 + tid;
    __builtin_amdgcn_global_load_lds(
        (const __attribute__((address_space(1))) void*)(src + idx * 4),
        (__attribute__((address_space(3))) void*)(dst + idx * 16),
        16, 0, 0);
  }
}

// ---- Phase 0: nt-stream X/XF, pack fp8, and MANUALLY SPILL each fragL[KK]
// to a thread-private LDS slot as produced. Rounds 6/8 lesson: holding
// fragL[16] (32 regs) live across the nt-stream exceeds the 128-arch-reg cap
// (50:50 arch/acc split at (256,2)) -> 650 MB scratch traffic; sched fences
// don't fix a requirement. With per-KK LDS writes, P0's live set is ~30 regs
// independent of scheduling; the pressure peak moves to the chunk phase,
// which fit at VGPR 100 in round 3. ----
template <int KK>
struct P0 {
  static __device__ __forceinline__ void run(const float* __restrict__ xr,
                                             const float* __restrict__ fr,
                                             int g, char* fbase, float& sumsq) {
    const f32x4 a0 = ntload4(xr + KK * 32 + 4 * g);
    const f32x4 b0 = ntload4(fr + KK * 32 + 4 * g);
    const f32x4 a1 = ntload4(xr + KK * 32 + 16 + 4 * g);
    const f32x4 b1 = ntload4(fr + KK * 32 + 16 + 4 * g);
    float d0 = a0[0] - b0[0], d1 = a0[1] - b0[1], d2 = a0[2] - b0[2], d3 = a0[3] - b0[3];
    float d4 = a1[0] - b1[0], d5 = a1[1] - b1[1], d6 = a1[2] - b1[2], d7 = a1[3] - b1[3];
    sumsq += d0*d0 + d1*d1 + d2*d2 + d3*d3 + d4*d4 + d5*d5 + d6*d6 + d7*d7;
    int lo = __builtin_amdgcn_cvt_pk_fp8_f32(d0, d1, 0, false);
    lo     = __builtin_amdgcn_cvt_pk_fp8_f32(d2, d3, lo, true);
    int hi = __builtin_amdgcn_cvt_pk_fp8_f32(d4, d5, 0, false);
    hi     = __builtin_amdgcn_cvt_pk_fp8_f32(d6, d7, hi, true);
    long long L = (long long)(((unsigned long long)(unsigned)hi << 32) | (unsigned)lo);
    *(long long*)(fbase + KK * 8) = L;          // ds_write_b64: frees the regs
    __builtin_amdgcn_sched_barrier(0);          // keep load clusters small
    P0<KK + 1>::run(xr, fr, g, fbase, sumsq);
  }
};
template <>
struct P0<16> {
  static __device__ __forceinline__ void run(const float*, const float*, int,
                                             char*, float&) {}
};

// ---- K-loop over 8 atom-steps; each b128 feeds two fp8 MFMAs ----
template <int P>
struct KLoop {
  static __device__ __forceinline__ void run(const char* __restrict__ rowbase,
                                             int g, int m,
                                             const long long (&fragL)[16],
                                             f32x4& c0, f32x4& c1) {
    int off = ((4 * P + g + m) & 31) * 16;           // rotated atom slot
    i32x4 a = *(const i32x4*)(rowbase + off);
    long long A0 = (long long)(((unsigned long long)(unsigned)a[1] << 32) | (unsigned)a[0]);
    long long A1 = (long long)(((unsigned long long)(unsigned)a[3] << 32) | (unsigned)a[2]);
    c0 = __builtin_amdgcn_mfma_f32_16x16x32_fp8_fp8(A0, fragL[2 * P],     c0, 0, 0, 0);
    c1 = __builtin_amdgcn_mfma_f32_16x16x32_fp8_fp8(A1, fragL[2 * P + 1], c1, 0, 0, 0);
    KLoop<P + 1>::run(rowbase, g, m, fragL, c0, c1);
  }
};
template <>
struct KLoop<8> {
  static __device__ __forceinline__ void run(const char*, int, int,
                                             const long long (&)[16], f32x4&, f32x4&) {}
};

// ---- Chunk loop: 3-buffer LDS ring, depth-2 prefetch, ONE raw s_barrier per
// chunk with counted vmcnt (round-3-validated pattern, re-derived for depth 2).
// At ChunkLoop<EB>'s wait: youngest stage in flight is stage(EB+1) (2 loads)
// -> vmcnt(2) guarantees stage(EB) complete (in-order retirement; P0's loads
// all retired before ChunkLoop<0>). stage(EB+2), issued after the barrier,
// overwrites buf[(EB+2)%3] = buf[(EB-1)%3]; all waves' reads of that buffer
// drained by the lgkmcnt(0)+barrier they just passed. ----
template <int EB>
struct ChunkLoop {
  static __device__ __forceinline__ void run(const uint32_t* __restrict__ ws,
                                             char* __restrict__ sbase,
                                             int tid, int m, int g,
                                             const long long (&fragL)[16], float& part) {
    if constexpr (EB < N_CHUNKS - 1)
      asm volatile("s_waitcnt vmcnt(2) lgkmcnt(0)" ::: "memory");
    else
      asm volatile("s_waitcnt vmcnt(0) lgkmcnt(0)" ::: "memory");
    __builtin_amdgcn_s_barrier();

    if constexpr (EB + PREFETCH < N_CHUNKS)
      stage_chunk(ws, EB + PREFETCH,
                  sbase + ((EB + PREFETCH) % N_BUF) * CHUNK_BYTES, tid);

    const char* rowbase = sbase + (EB % N_BUF) * CHUNK_BYTES + m * 512;
    f32x4 c0 = {0.f, 0.f, 0.f, 0.f}, c1 = {0.f, 0.f, 0.f, 0.f};
    KLoop<0>::run(rowbase, g, m, fragL, c0, c1);

    // Epilogue: C row (g*4+i)=e_local; delta[r][e] is byte (EB&1)*4+i of fragL[EB>>1].
    constexpr int kk = EB >> 1;
    int src = (int)(fragL[kk] >> ((EB & 1) * 32));
    f32x2 f01 = __builtin_amdgcn_cvt_pk_f32_fp8(src, false);
    f32x2 f23 = __builtin_amdgcn_cvt_pk_f32_fp8(src, true);
    part += (c0[0] + c1[0]) * f01[0] + (c0[1] + c1[1]) * f01[1]
          + (c0[2] + c1[2]) * f23[0] + (c0[3] + c1[3]) * f23[1];

    ChunkLoop<EB + 1>::run(ws, sbase, tid, m, g, fragL, part);
  }
};
template <>
struct ChunkLoop<N_CHUNKS> {
  static __device__ __forceinline__ void run(const uint32_t*, char*, int, int, int,
                                             const long long (&)[16], float&) {}
};

// out[row] = fp32 sumsq(delta) + (1/64) * delta^T (64R) delta  via fp8 MFMA.
// Fused: nt-stream (round-5 fix) + LDS frag-spill (round-8 fix) + counted-vmcnt
// ring (round-3). LDS: 24576 ring + 34816 frag = 59392 B -> 2 blocks/CU.
__global__ __launch_bounds__(256, 2)
void mahal_main(const float* __restrict__ X, const float* __restrict__ XF,
                const uint32_t* __restrict__ ws, float* __restrict__ out) {
  __shared__ __align__(16) char sA[N_BUF][CHUNK_BYTES];   // 24 KB ring
  __shared__ __align__(16) char sF[256 * FRAG_STRIDE];    // 34 KB frag spill

  const int tid  = threadIdx.x;
  const int lane = tid & 63;
  const int wv   = tid >> 6;
  const int m    = lane & 15;          // delta row within wave
  const int g    = lane >> 4;          // lane group
  const int row  = blockIdx.x * ROWS_PER_BLOCK + wv * 16 + m;

  const float* xr = X  + (size_t)row * DIM;
  const float* fr = XF + (size_t)row * DIM;

  // Prologue: 2 chunks in flight; they complete under P0's stream.
  stage_chunk(ws, 0, sA[0], tid);
  stage_chunk(ws, 1, sA[1], tid);

  char* fbase = sF + tid * FRAG_STRIDE;
  float sumsq = 0.f;
  P0<0>::run(xr, fr, g, fbase, sumsq);
  sumsq += __shfl_xor(sumsq, 16);
  sumsq += __shfl_xor(sumsq, 32);

  // Block store-to-load forwarding: without this clobber the compiler may
  // forward the LDS writes into the reads and resurrect the 32-reg live range.
  asm volatile("" ::: "memory");

  long long fragL[16];
#pragma unroll
  for (int k = 0; k < 16; ++k)
    fragL[k] = *(const long long*)(fbase + k * 8);

  float part = 0.f;
  ChunkLoop<0>::run(ws, &sA[0][0], tid, m, g, fragL, part);

  part += __shfl_xor(part, 16);
  part += __shfl_xor(part, 32);
  if (g == 0) out[row] = sumsq + part * 0.015625f;   // 1/64 undoes R scaling
}

// Safety-net (only if ws_size is unexpectedly small): naive fp32, correct.
__global__ void mahal_naive(const float* __restrict__ X, const float* __restrict__ XF,
                            const float* __restrict__ S, float* __restrict__ out, int n) {
  int row = blockIdx.x * blockDim.x + threadIdx.x;
  if (row >= n) return;
  const float* xr = X + (size_t)row * DIM;
  const float* fr = XF + (size_t)row * DIM;
  float acc = 0.f;
  for (int d = 0; d < DIM; ++d) {
    float dd = xr[d] - fr[d];
    float inner = 0.f;
    for (int e = 0; e < DIM; ++e) inner += S[d * DIM + e] * (xr[e] - fr[e]);
    acc += dd * inner;
  }
  out[row] = acc;
}

extern "C" void kernel_launch(void* const* d_in, const int* in_sizes, int n_in,
                              void* d_out, int out_size, void* d_ws, size_t ws_size,
                              hipStream_t stream) {
  const float* X  = (const float*)d_in[0];
  const float* XF = (const float*)d_in[1];
  const float* S  = (const float*)d_in[2];
  float* out = (float*)d_out;
  const int N = in_sizes[0] / DIM;

  if (ws_size < (size_t)WS_BYTES || (N % ROWS_PER_BLOCK) != 0) {
    mahal_naive<<<(N + 63) / 64, 64, 0, stream>>>(X, XF, S, out, N);
    return;
  }

  uint32_t* ws = (uint32_t*)d_ws;
  prep_R<<<(WS_BYTES / 4 + 255) / 256, 256, 0, stream>>>(S, ws);
  mahal_main<<<N / ROWS_PER_BLOCK, 256, 0, stream>>>(X, XF, ws, out);
}